// Round 1
// baseline (69.792 us; speedup 1.0000x reference)
//
#include <hip/hip_runtime.h>
#include <math.h>

#define NG    512
#define IMG_W 256
#define IMG_H 192

#define NEAR_P    0.1f
#define FAR_P     100.0f
#define ALPHA_MAX 0.99f

// Workspace layout (floats): 9 sorted SoA arrays of NG, then 1 int nvis.
// [0..NG)   ca   (conic a)
// [NG..2NG) cb   (conic b)
// [2NG..3NG)cc   (conic c)
// [3NG..4NG)mx
// [4NG..5NG)my
// [5NG..6NG)op   (sigmoid opacity, 0 if invisible)
// [6NG..7NG)r  [7NG..8NG)g  [8NG..9NG)b
// ws[9NG] as int: nvis

__global__ __launch_bounds__(NG) void gs_preprocess(
    const float* __restrict__ pos,
    const float* __restrict__ scl,
    const float* __restrict__ rot,
    const float* __restrict__ opa,
    const float* __restrict__ col,
    const float* __restrict__ vm,
    const int*   __restrict__ fov,
    float* __restrict__ ws)
{
    __shared__ float s_ca[NG], s_cb[NG], s_cc[NG], s_mx[NG], s_my[NG];
    __shared__ float s_op[NG], s_r[NG], s_g[NG], s_b[NG];
    __shared__ float s_key[NG];
    __shared__ int   s_idx[NG];
    __shared__ int   s_nvis;

    const int g = threadIdx.x;
    if (g == 0) s_nvis = 0;

    // ---- quaternion -> rotation ----
    float qw = rot[g*4+0], qx = rot[g*4+1], qy = rot[g*4+2], qz = rot[g*4+3];
    float qn = sqrtf(qw*qw + qx*qx + qy*qy + qz*qz);
    qw /= qn; qx /= qn; qy /= qn; qz /= qn;
    float R00 = 1.f - 2.f*(qy*qy + qz*qz);
    float R01 = 2.f*(qx*qy - qw*qz);
    float R02 = 2.f*(qx*qz + qw*qy);
    float R10 = 2.f*(qx*qy + qw*qz);
    float R11 = 1.f - 2.f*(qx*qx + qz*qz);
    float R12 = 2.f*(qy*qz - qw*qx);
    float R20 = 2.f*(qx*qz - qw*qy);
    float R21 = 2.f*(qy*qz + qw*qx);
    float R22 = 1.f - 2.f*(qx*qx + qy*qy);

    // ---- cov3d = R diag(s^2) R^T ----
    float s0 = scl[g*3+0], s1 = scl[g*3+1], s2 = scl[g*3+2];
    float q0 = s0*s0, q1 = s1*s1, q2 = s2*s2;
    float C00 = R00*R00*q0 + R01*R01*q1 + R02*R02*q2;
    float C01 = R00*R10*q0 + R01*R11*q1 + R02*R12*q2;
    float C02 = R00*R20*q0 + R01*R21*q1 + R02*R22*q2;
    float C11 = R10*R10*q0 + R11*R11*q1 + R12*R12*q2;
    float C12 = R10*R20*q0 + R11*R21*q1 + R12*R22*q2;
    float C22 = R20*R20*q0 + R21*R21*q1 + R22*R22*q2;

    // ---- camera transform ----
    float W00 = vm[0],  W01 = vm[1],  W02 = vm[2],  t0 = vm[3];
    float W10 = vm[4],  W11 = vm[5],  W12 = vm[6],  t1 = vm[7];
    float W20 = vm[8],  W21 = vm[9],  W22 = vm[10], t2 = vm[11];
    float px = pos[g*3+0], py = pos[g*3+1], pz = pos[g*3+2];
    float X = W00*px + W01*py + W02*pz + t0;
    float Y = W10*px + W11*py + W12*pz + t1;
    float Z = W20*px + W21*py + W22*pz + t2;

    float depth = Z;
    float zs = fmaxf(depth, NEAR_P);

    // fx from fov (int degrees), double to match numpy host math
    double fovd = (double)fov[0];
    float fx = (float)((double)IMG_W / (2.0 * tan(fovd * M_PI / 180.0 / 2.0)));

    float mx = fx * X / zs + (float)IMG_W / 2.0f;
    float my = (float)IMG_H / 2.0f - fx * Y / zs;

    // ---- J (2x3), T = J @ Wr (2x3) ----
    float j00 = fx / zs;
    float j02 = -fx * X / (zs * zs);
    float j11 = fx / zs;
    float j12 = -fx * Y / (zs * zs);
    float T00 = j00*W00 + j02*W20;
    float T01 = j00*W01 + j02*W21;
    float T02 = j00*W02 + j02*W22;
    float T10 = j11*W10 + j12*W20;
    float T11 = j11*W11 + j12*W21;
    float T12 = j11*W12 + j12*W22;

    // ---- cov2d = T C T^T ----
    // u = C @ T0, v = C @ T1
    float u0 = C00*T00 + C01*T01 + C02*T02;
    float u1 = C01*T00 + C11*T01 + C12*T02;
    float u2 = C02*T00 + C12*T01 + C22*T02;
    float v0 = C00*T10 + C01*T11 + C02*T12;
    float v1 = C01*T10 + C11*T11 + C12*T12;
    float v2 = C02*T10 + C12*T11 + C22*T12;
    float a = T00*u0 + T01*u1 + T02*u2;
    float bcov = 0.5f * ((T00*v0 + T01*v1 + T02*v2) + (T10*u0 + T11*u1 + T12*u2));
    float c = T10*v0 + T11*v1 + T12*v2;

    // ---- eigen clamp ----
    float mean_e = 0.5f * (a + c);
    float disc = sqrtf(fmaxf(0.25f*(a - c)*(a - c) + bcov*bcov, 0.0f));
    float min_eig = mean_e - disc;
    float eps = (min_eig <= 0.0f) ? (fabsf(min_eig) + 1e-6f) : 0.0f;
    a += eps; c += eps;
    float max_eig = mean_e + eps + disc;
    float radii = ceilf(3.0f * sqrtf(fmaxf(max_eig, 1e-6f)));

    bool visible = (depth > NEAR_P) && (depth < FAR_P) && (radii > 0.0f);

    float det = fmaxf(a*c - bcov*bcov, 1e-12f);
    float ca = c / det, cbv = -bcov / det, cc = a / det;

    float op = 1.0f / (1.0f + expf(-opa[g]));

    s_ca[g] = ca;  s_cb[g] = cbv; s_cc[g] = cc;
    s_mx[g] = mx;  s_my[g] = my;
    s_op[g] = visible ? op : 0.0f;
    s_r[g] = col[g*3+0]; s_g[g] = col[g*3+1]; s_b[g] = col[g*3+2];
    s_key[g] = visible ? -depth : INFINITY;
    s_idx[g] = g;
    if (visible) atomicAdd(&s_nvis, 1);

    __syncthreads();

    // ---- bitonic sort on (key, idx), ascending — reproduces stable argsort ----
    for (int k = 2; k <= NG; k <<= 1) {
        for (int j = k >> 1; j > 0; j >>= 1) {
            int i = threadIdx.x;
            int ixj = i ^ j;
            if (ixj > i) {
                bool up = ((i & k) == 0);
                float ki = s_key[i], kj = s_key[ixj];
                int   ii = s_idx[i], ij = s_idx[ixj];
                bool gt = (ki > kj) || (ki == kj && ii > ij);
                bool sw = up ? gt : !gt;
                if (sw) {
                    s_key[i] = kj; s_key[ixj] = ki;
                    s_idx[i] = ij; s_idx[ixj] = ii;
                }
            }
            __syncthreads();
        }
    }

    // ---- gather into sorted SoA in workspace ----
    int src = s_idx[g];
    ws[0*NG + g] = s_ca[src];
    ws[1*NG + g] = s_cb[src];
    ws[2*NG + g] = s_cc[src];
    ws[3*NG + g] = s_mx[src];
    ws[4*NG + g] = s_my[src];
    ws[5*NG + g] = s_op[src];
    ws[6*NG + g] = s_r[src];
    ws[7*NG + g] = s_g[src];
    ws[8*NG + g] = s_b[src];
    if (g == 0) ((int*)ws)[9*NG] = s_nvis;
}

__global__ __launch_bounds__(IMG_W) void gs_render(
    const float* __restrict__ ws,
    const float* __restrict__ bg,
    float* __restrict__ out)
{
    __shared__ float s[9*NG];
    __shared__ int s_n;
    for (int i = threadIdx.x; i < 9*NG; i += blockDim.x) s[i] = ws[i];
    if (threadIdx.x == 0) s_n = ((const int*)ws)[9*NG];
    __syncthreads();

    const float* ca = s + 0*NG;
    const float* cb = s + 1*NG;
    const float* cc = s + 2*NG;
    const float* mx = s + 3*NG;
    const float* my = s + 4*NG;
    const float* op = s + 5*NG;
    const float* cr = s + 6*NG;
    const float* cg = s + 7*NG;
    const float* cbl= s + 8*NG;

    const int x = threadIdx.x;
    const int y = blockIdx.x;
    const float fx_ = (float)x;
    const float fy_ = (float)y;

    float Tr = 1.0f;
    float accr = 0.f, accg = 0.f, accb = 0.f;
    const int nv = s_n;
    for (int i = 0; i < nv; ++i) {
        float dx = fx_ - mx[i];
        float dy = fy_ - my[i];
        float qv = ca[i]*dx*dx + 2.0f*cb[i]*dx*dy + cc[i]*dy*dy;
        float G = expf(-0.5f * fmaxf(qv, 0.0f));
        float alpha = fminf(op[i] * G, ALPHA_MAX);
        float w = alpha * Tr;
        accr += w * cr[i];
        accg += w * cg[i];
        accb += w * cbl[i];
        Tr *= (1.0f - alpha);
    }

    const int pix = y * IMG_W + x;
    out[pix*3 + 0] = accr + Tr * bg[0];
    out[pix*3 + 1] = accg + Tr * bg[1];
    out[pix*3 + 2] = accb + Tr * bg[2];
}

extern "C" void kernel_launch(void* const* d_in, const int* in_sizes, int n_in,
                              void* d_out, int out_size, void* d_ws, size_t ws_size,
                              hipStream_t stream) {
    const float* pos = (const float*)d_in[0];
    const float* scl = (const float*)d_in[1];
    const float* rot = (const float*)d_in[2];
    const float* opa = (const float*)d_in[3];
    const float* col = (const float*)d_in[4];
    const float* vm  = (const float*)d_in[5];
    const float* bgp = (const float*)d_in[6];
    const int*   fov = (const int*)d_in[7];

    float* ws  = (float*)d_ws;
    float* out = (float*)d_out;

    gs_preprocess<<<1, NG, 0, stream>>>(pos, scl, rot, opa, col, vm, fov, ws);
    gs_render<<<IMG_H, IMG_W, 0, stream>>>(ws, bgp, out);
}

// Round 2
// 29.025 us; speedup vs baseline: 2.4045x; 2.4045x over previous
//
#include <hip/hip_runtime.h>
#include <math.h>

#define NG    512
#define IMG_W 256
#define IMG_H 192

#define NEAR_P    0.1f
#define FAR_P     100.0f
#define ALPHA_MAX 0.99f

#define PIX_PER_BLK 64
#define CHUNKS      4
#define RBLOCK      256   // PIX_PER_BLK * CHUNKS

// Workspace: NG records of 3 float4 (48 B), depth-sorted:
//  rec[0] = { A=-0.5*conic_a, B=-conic_b, C=-0.5*conic_c, mx }
//  rec[1] = { my, op (0 if invisible), col_r, col_g }
//  rec[2] = { col_b, r5 = 5*sqrt(max_eig), 0, 0 }
// Invisible: op=0, my=1e30 (fails cull test everywhere).

__global__ __launch_bounds__(NG) void gs_preprocess(
    const float* __restrict__ pos,
    const float* __restrict__ scl,
    const float* __restrict__ rot,
    const float* __restrict__ opa,
    const float* __restrict__ col,
    const float* __restrict__ vm,
    const int*   __restrict__ fov,
    float4* __restrict__ ws)
{
    __shared__ float s_A[NG], s_B[NG], s_C[NG], s_mx[NG], s_my[NG];
    __shared__ float s_op[NG], s_r[NG], s_g[NG], s_b[NG], s_r5[NG];
    __shared__ float s_key[NG];
    __shared__ int   s_idx[NG];

    const int g = threadIdx.x;

    // ---- quaternion -> rotation ----
    float qw = rot[g*4+0], qx = rot[g*4+1], qy = rot[g*4+2], qz = rot[g*4+3];
    float qn = sqrtf(qw*qw + qx*qx + qy*qy + qz*qz);
    qw /= qn; qx /= qn; qy /= qn; qz /= qn;
    float R00 = 1.f - 2.f*(qy*qy + qz*qz);
    float R01 = 2.f*(qx*qy - qw*qz);
    float R02 = 2.f*(qx*qz + qw*qy);
    float R10 = 2.f*(qx*qy + qw*qz);
    float R11 = 1.f - 2.f*(qx*qx + qz*qz);
    float R12 = 2.f*(qy*qz - qw*qx);
    float R20 = 2.f*(qx*qz - qw*qy);
    float R21 = 2.f*(qy*qz + qw*qx);
    float R22 = 1.f - 2.f*(qx*qx + qy*qy);

    // ---- cov3d = R diag(s^2) R^T ----
    float s0 = scl[g*3+0], s1 = scl[g*3+1], s2 = scl[g*3+2];
    float q0 = s0*s0, q1 = s1*s1, q2 = s2*s2;
    float C00 = R00*R00*q0 + R01*R01*q1 + R02*R02*q2;
    float C01 = R00*R10*q0 + R01*R11*q1 + R02*R12*q2;
    float C02 = R00*R20*q0 + R01*R21*q1 + R02*R22*q2;
    float C11 = R10*R10*q0 + R11*R11*q1 + R12*R12*q2;
    float C12 = R10*R20*q0 + R11*R21*q1 + R12*R22*q2;
    float C22 = R20*R20*q0 + R21*R21*q1 + R22*R22*q2;

    // ---- camera transform ----
    float W00 = vm[0],  W01 = vm[1],  W02 = vm[2],  t0 = vm[3];
    float W10 = vm[4],  W11 = vm[5],  W12 = vm[6],  t1 = vm[7];
    float W20 = vm[8],  W21 = vm[9],  W22 = vm[10], t2 = vm[11];
    float px = pos[g*3+0], py = pos[g*3+1], pz = pos[g*3+2];
    float X = W00*px + W01*py + W02*pz + t0;
    float Y = W10*px + W11*py + W12*pz + t1;
    float Z = W20*px + W21*py + W22*pz + t2;

    float depth = Z;
    float zs = fmaxf(depth, NEAR_P);

    double fovd = (double)fov[0];
    float fx = (float)((double)IMG_W / (2.0 * tan(fovd * M_PI / 180.0 / 2.0)));

    float mx = fx * X / zs + (float)IMG_W / 2.0f;
    float my = (float)IMG_H / 2.0f - fx * Y / zs;

    // ---- T = J @ Wr (2x3) ----
    float j00 = fx / zs;
    float j02 = -fx * X / (zs * zs);
    float j11 = fx / zs;
    float j12 = -fx * Y / (zs * zs);
    float T00 = j00*W00 + j02*W20;
    float T01 = j00*W01 + j02*W21;
    float T02 = j00*W02 + j02*W22;
    float T10 = j11*W10 + j12*W20;
    float T11 = j11*W11 + j12*W21;
    float T12 = j11*W12 + j12*W22;

    // ---- cov2d = T C T^T ----
    float u0 = C00*T00 + C01*T01 + C02*T02;
    float u1 = C01*T00 + C11*T01 + C12*T02;
    float u2 = C02*T00 + C12*T01 + C22*T02;
    float v0 = C00*T10 + C01*T11 + C02*T12;
    float v1 = C01*T10 + C11*T11 + C12*T12;
    float v2 = C02*T10 + C12*T11 + C22*T12;
    float a = T00*u0 + T01*u1 + T02*u2;
    float bcov = 0.5f * ((T00*v0 + T01*v1 + T02*v2) + (T10*u0 + T11*u1 + T12*u2));
    float c = T10*v0 + T11*v1 + T12*v2;

    // ---- eigen clamp ----
    float mean_e = 0.5f * (a + c);
    float disc = sqrtf(fmaxf(0.25f*(a - c)*(a - c) + bcov*bcov, 0.0f));
    float min_eig = mean_e - disc;
    float eps = (min_eig <= 0.0f) ? (fabsf(min_eig) + 1e-6f) : 0.0f;
    a += eps; c += eps;
    float max_eig = mean_e + eps + disc;
    float radii = ceilf(3.0f * sqrtf(fmaxf(max_eig, 1e-6f)));

    bool visible = (depth > NEAR_P) && (depth < FAR_P) && (radii > 0.0f);

    float det = fmaxf(a*c - bcov*bcov, 1e-12f);
    float ca = c / det, cbv = -bcov / det, cc = a / det;

    float op = 1.0f / (1.0f + __expf(-opa[g]));
    float r5 = 5.0f * sqrtf(fmaxf(max_eig, 1e-6f));

    s_A[g]  = -0.5f * ca;
    s_B[g]  = -cbv;
    s_C[g]  = -0.5f * cc;
    s_mx[g] = mx;
    s_my[g] = visible ? my : 1e30f;
    s_op[g] = visible ? op : 0.0f;
    s_r[g]  = col[g*3+0];
    s_g[g]  = col[g*3+1];
    s_b[g]  = col[g*3+2];
    s_r5[g] = visible ? r5 : 0.0f;
    s_key[g] = visible ? -depth : INFINITY;
    s_idx[g] = g;

    __syncthreads();

    // ---- bitonic sort on (key, idx) ascending == stable argsort ----
    for (int k = 2; k <= NG; k <<= 1) {
        for (int j = k >> 1; j > 0; j >>= 1) {
            int i = threadIdx.x;
            int ixj = i ^ j;
            if (ixj > i) {
                bool up = ((i & k) == 0);
                float ki = s_key[i], kj = s_key[ixj];
                int   ii = s_idx[i], ij = s_idx[ixj];
                bool gt = (ki > kj) || (ki == kj && ii > ij);
                bool sw = up ? gt : !gt;
                if (sw) {
                    s_key[i] = kj; s_key[ixj] = ki;
                    s_idx[i] = ij; s_idx[ixj] = ii;
                }
            }
            __syncthreads();
        }
    }

    int src = s_idx[g];
    ws[3*g+0] = make_float4(s_A[src], s_B[src], s_C[src], s_mx[src]);
    ws[3*g+1] = make_float4(s_my[src], s_op[src], s_r[src], s_g[src]);
    ws[3*g+2] = make_float4(s_b[src], s_r5[src], 0.0f, 0.0f);
}

__global__ __launch_bounds__(RBLOCK) void gs_render(
    const float4* __restrict__ ws,
    const float* __restrict__ bg,
    float* __restrict__ out)
{
    __shared__ float4 sg[NG*3];                    // 24 KB
    __shared__ int    s_list[NG];                  // compacted survivor indices
    __shared__ int    s_wtot[4], s_woff[4], s_M;
    __shared__ float4 s_part[CHUNKS][PIX_PER_BLK]; // rgbT partials
    __shared__ float  s_out[PIX_PER_BLK*3];

    const int tid = threadIdx.x;

    for (int i = tid; i < NG*3; i += RBLOCK) sg[i] = ws[i];
    __syncthreads();

    const int   b  = blockIdx.x;
    const float yf = (float)(b >> 2);                  // row (4 strips/row)
    const float x0 = (float)((b & 3) * PIX_PER_BLK);   // strip start column

    // ---- 5-sigma strip cull, order-preserving ballot compaction ----
    const int g0 = 2*tid, g1 = 2*tid+1;
    float mx0 = sg[3*g0+0].w, my0 = sg[3*g0+1].x, r50 = sg[3*g0+2].y;
    float mx1 = sg[3*g1+0].w, my1 = sg[3*g1+1].x, r51 = sg[3*g1+2].y;
    bool p0 = (fabsf(my0 - yf) <= r50) & (mx0 >= x0 - r50) & (mx0 <= x0 + 63.0f + r50);
    bool p1 = (fabsf(my1 - yf) <= r51) & (mx1 >= x0 - r51) & (mx1 <= x0 + 63.0f + r51);

    unsigned long long m0 = __ballot(p0);
    unsigned long long m1 = __ballot(p1);
    const int lane = tid & 63;
    const int wv   = tid >> 6;
    unsigned long long lt = (1ull << lane) - 1ull;

    if (lane == 0) s_wtot[wv] = __popcll(m0) + __popcll(m1);
    __syncthreads();
    if (tid == 0) {
        int acc = 0;
        for (int i = 0; i < 4; ++i) { s_woff[i] = acc; acc += s_wtot[i]; }
        s_M = acc;
    }
    __syncthreads();
    int basep = s_woff[wv] + __popcll(m0 & lt) + __popcll(m1 & lt);
    if (p0) s_list[basep] = g0;
    if (p1) s_list[basep + (p0 ? 1 : 0)] = g1;
    __syncthreads();

    // ---- chunked composite ----
    const int M  = s_M;
    const int qn = (M + CHUNKS - 1) / CHUNKS;
    const int lpix  = tid & 63;
    const int chunk = tid >> 6;
    int start = chunk * qn; if (start > M) start = M;
    int end   = start + qn; if (end > M) end = M;

    const float fxp = x0 + (float)lpix;

    float Tr = 1.0f, ar = 0.0f, ag = 0.0f, abv = 0.0f;
    for (int i = start; i < end; ++i) {
        int gi = s_list[i];
        float4 r0 = sg[3*gi+0];
        float4 r1 = sg[3*gi+1];
        float  bc = sg[3*gi+2].x;
        float dx = fxp - r0.w;
        float dy = yf  - r1.x;
        float qv = (r0.x*dx)*dx + (r0.y*dx)*dy + (r0.z*dy)*dy; // = -0.5*q
        float G = __expf(fminf(qv, 0.0f));
        float alpha = fminf(r1.y * G, ALPHA_MAX);
        float wgt = alpha * Tr;
        ar  += wgt * r1.z;
        ag  += wgt * r1.w;
        abv += wgt * bc;
        Tr  *= (1.0f - alpha);
    }
    s_part[chunk][lpix] = make_float4(ar, ag, abv, Tr);
    __syncthreads();

    if (chunk == 0) {
        float4 c0 = s_part[0][lpix], c1 = s_part[1][lpix];
        float4 c2 = s_part[2][lpix], c3 = s_part[3][lpix];
        float T0 = c0.w, T01 = T0*c1.w, T012 = T01*c2.w, Tall = T012*c3.w;
        float r  = c0.x + T0*c1.x + T01*c2.x + T012*c3.x;
        float gc = c0.y + T0*c1.y + T01*c2.y + T012*c3.y;
        float bb = c0.z + T0*c1.z + T01*c2.z + T012*c3.z;
        s_out[3*lpix+0] = r  + Tall * bg[0];
        s_out[3*lpix+1] = gc + Tall * bg[1];
        s_out[3*lpix+2] = bb + Tall * bg[2];
    }
    __syncthreads();
    if (tid < PIX_PER_BLK*3)
        out[b * (PIX_PER_BLK*3) + tid] = s_out[tid];
}

extern "C" void kernel_launch(void* const* d_in, const int* in_sizes, int n_in,
                              void* d_out, int out_size, void* d_ws, size_t ws_size,
                              hipStream_t stream) {
    const float* pos = (const float*)d_in[0];
    const float* scl = (const float*)d_in[1];
    const float* rot = (const float*)d_in[2];
    const float* opa = (const float*)d_in[3];
    const float* col = (const float*)d_in[4];
    const float* vm  = (const float*)d_in[5];
    const float* bgp = (const float*)d_in[6];
    const int*   fov = (const int*)d_in[7];

    float4* ws  = (float4*)d_ws;
    float*  out = (float*)d_out;

    gs_preprocess<<<1, NG, 0, stream>>>(pos, scl, rot, opa, col, vm, fov, ws);
    gs_render<<<(IMG_H*IMG_W)/PIX_PER_BLK, RBLOCK, 0, stream>>>(ws, bgp, out);
}

// Round 3
// 23.815 us; speedup vs baseline: 2.9305x; 1.2187x over previous
//
#include <hip/hip_runtime.h>
#include <math.h>

#define NG    512
#define IMG_W 256
#define IMG_H 192

#define NEAR_P    0.1f
#define FAR_P     100.0f
#define ALPHA_MAX 0.99f

#define PIX     64     // pixels per block (one row strip)
#define CHUNKS  4
#define TPB     256    // PIX * CHUNKS

// One fused kernel: every block redundantly preprocesses all NG gaussians
// into LDS, culls to its 64x1 strip, rank-sorts the survivors by depth
// (stable, matching the reference argsort restricted to survivors), then
// composites with a 4-way transmittance-split scan.

__global__ __launch_bounds__(TPB) void gs_fused(
    const float* __restrict__ pos,
    const float* __restrict__ scl,
    const float* __restrict__ rot,
    const float* __restrict__ opa,
    const float* __restrict__ col,
    const float* __restrict__ vm,
    const int*   __restrict__ fov,
    const float* __restrict__ bg,
    float* __restrict__ out)
{
    __shared__ float4 s_rec0[NG];            // A=-0.5ca, B=-cb, C=-0.5cc, mx
    __shared__ float4 s_rec1[NG];            // my, op(0 if invis), col_r, col_g
    __shared__ float  s_bcol[NG];            // col_b
    __shared__ float  s_mx[NG], s_my[NG], s_r5[NG], s_key[NG];
    __shared__ float  s_key2[NG];            // compacted keys
    __shared__ unsigned short s_list[NG];    // compacted gaussian ids (asc. id)
    __shared__ unsigned short s_order[NG];   // depth-ordered gaussian ids
    __shared__ int    s_wtot[4], s_woff[4], s_M;
    __shared__ float4 s_part[CHUNKS][PIX];
    __shared__ float  s_out[PIX*3];

    const int tid = threadIdx.x;

    const float fx = (float)IMG_W /
        (2.0f * tanf((float)fov[0] * (float)(M_PI / 180.0) * 0.5f));

    const float W00 = vm[0],  W01 = vm[1],  W02 = vm[2],  t0 = vm[3];
    const float W10 = vm[4],  W11 = vm[5],  W12 = vm[6],  t1 = vm[7];
    const float W20 = vm[8],  W21 = vm[9],  W22 = vm[10], t2 = vm[11];

    // ---- per-gaussian preprocessing (2 per thread) ----
    for (int g = tid; g < NG; g += TPB) {
        float qw = rot[g*4+0], qx = rot[g*4+1], qy = rot[g*4+2], qz = rot[g*4+3];
        float qn = sqrtf(qw*qw + qx*qx + qy*qy + qz*qz);
        qw /= qn; qx /= qn; qy /= qn; qz /= qn;
        float R00 = 1.f - 2.f*(qy*qy + qz*qz);
        float R01 = 2.f*(qx*qy - qw*qz);
        float R02 = 2.f*(qx*qz + qw*qy);
        float R10 = 2.f*(qx*qy + qw*qz);
        float R11 = 1.f - 2.f*(qx*qx + qz*qz);
        float R12 = 2.f*(qy*qz - qw*qx);
        float R20 = 2.f*(qx*qz - qw*qy);
        float R21 = 2.f*(qy*qz + qw*qx);
        float R22 = 1.f - 2.f*(qx*qx + qy*qy);

        float s0 = scl[g*3+0], s1 = scl[g*3+1], s2 = scl[g*3+2];
        float q0 = s0*s0, q1 = s1*s1, q2 = s2*s2;
        float C00 = R00*R00*q0 + R01*R01*q1 + R02*R02*q2;
        float C01 = R00*R10*q0 + R01*R11*q1 + R02*R12*q2;
        float C02 = R00*R20*q0 + R01*R21*q1 + R02*R22*q2;
        float C11 = R10*R10*q0 + R11*R11*q1 + R12*R12*q2;
        float C12 = R10*R20*q0 + R11*R21*q1 + R12*R22*q2;
        float C22 = R20*R20*q0 + R21*R21*q1 + R22*R22*q2;

        float px = pos[g*3+0], py = pos[g*3+1], pz = pos[g*3+2];
        float X = W00*px + W01*py + W02*pz + t0;
        float Y = W10*px + W11*py + W12*pz + t1;
        float Z = W20*px + W21*py + W22*pz + t2;

        float depth = Z;
        float zs = fmaxf(depth, NEAR_P);

        float mx = fx * X / zs + (float)IMG_W * 0.5f;
        float my = (float)IMG_H * 0.5f - fx * Y / zs;

        float j00 = fx / zs;
        float j02 = -fx * X / (zs * zs);
        float j12 = -fx * Y / (zs * zs);
        float T00 = j00*W00 + j02*W20;
        float T01 = j00*W01 + j02*W21;
        float T02 = j00*W02 + j02*W22;
        float T10 = j00*W10 + j12*W20;
        float T11 = j00*W11 + j12*W21;
        float T12 = j00*W12 + j12*W22;

        float u0 = C00*T00 + C01*T01 + C02*T02;
        float u1 = C01*T00 + C11*T01 + C12*T02;
        float u2 = C02*T00 + C12*T01 + C22*T02;
        float v0 = C00*T10 + C01*T11 + C02*T12;
        float v1 = C01*T10 + C11*T11 + C12*T12;
        float v2 = C02*T10 + C12*T11 + C22*T12;
        float a    = T00*u0 + T01*u1 + T02*u2;
        float bcov = 0.5f * ((T00*v0 + T01*v1 + T02*v2) + (T10*u0 + T11*u1 + T12*u2));
        float c    = T10*v0 + T11*v1 + T12*v2;

        float mean_e = 0.5f * (a + c);
        float disc = sqrtf(fmaxf(0.25f*(a - c)*(a - c) + bcov*bcov, 0.0f));
        float min_eig = mean_e - disc;
        float eps = (min_eig <= 0.0f) ? (fabsf(min_eig) + 1e-6f) : 0.0f;
        a += eps; c += eps;
        float max_eig = mean_e + eps + disc;
        float radii = ceilf(3.0f * sqrtf(fmaxf(max_eig, 1e-6f)));

        bool visible = (depth > NEAR_P) && (depth < FAR_P) && (radii > 0.0f);

        float det = fmaxf(a*c - bcov*bcov, 1e-12f);
        float ca = c / det, cbv = -bcov / det, cc = a / det;
        float op = 1.0f / (1.0f + __expf(-opa[g]));
        float r5 = 5.0f * sqrtf(fmaxf(max_eig, 1e-6f));

        s_rec0[g] = make_float4(-0.5f*ca, -cbv, -0.5f*cc, mx);
        s_rec1[g] = make_float4(my, visible ? op : 0.0f, col[g*3+0], col[g*3+1]);
        s_bcol[g] = col[g*3+2];
        s_mx[g]  = mx;
        s_my[g]  = visible ? my : 1e30f;
        s_r5[g]  = visible ? r5 : 0.0f;
        s_key[g] = visible ? -depth : INFINITY;
    }
    __syncthreads();

    const int   b   = blockIdx.x;
    const float yf  = (float)(b >> 2);
    const float x0f = (float)((b & 3) * PIX);

    // ---- 5-sigma strip cull + order-preserving ballot compaction ----
    const int g0 = 2*tid, g1 = 2*tid+1;
    bool p0 = (fabsf(s_my[g0] - yf) <= s_r5[g0]) &
              (s_mx[g0] >= x0f - s_r5[g0]) & (s_mx[g0] <= x0f + 63.0f + s_r5[g0]);
    bool p1 = (fabsf(s_my[g1] - yf) <= s_r5[g1]) &
              (s_mx[g1] >= x0f - s_r5[g1]) & (s_mx[g1] <= x0f + 63.0f + s_r5[g1]);

    unsigned long long m0 = __ballot(p0);
    unsigned long long m1 = __ballot(p1);
    const int lane = tid & 63;
    const int wv   = tid >> 6;
    unsigned long long lt = (1ull << lane) - 1ull;

    if (lane == 0) s_wtot[wv] = __popcll(m0) + __popcll(m1);
    __syncthreads();
    if (tid == 0) {
        int acc = 0;
        for (int i = 0; i < 4; ++i) { s_woff[i] = acc; acc += s_wtot[i]; }
        s_M = acc;
    }
    __syncthreads();
    int basep = s_woff[wv] + __popcll(m0 & lt) + __popcll(m1 & lt);
    if (p0) { s_list[basep] = (unsigned short)g0; s_key2[basep] = s_key[g0]; }
    if (p1) { int p = basep + (p0 ? 1 : 0);
              s_list[p] = (unsigned short)g1; s_key2[p] = s_key[g1]; }
    __syncthreads();

    // ---- rank-sort survivors by (key, list-position) — stable depth order ----
    const int M = s_M;
    for (int t = tid; t < M; t += TPB) {
        float k = s_key2[t];
        int r = 0;
        for (int j = 0; j < M; ++j) {
            float kj = s_key2[j];
            r += (kj < k) || (kj == k && j < t);
        }
        s_order[r] = s_list[t];
    }
    __syncthreads();

    // ---- chunked composite ----
    const int qn = (M + CHUNKS - 1) / CHUNKS;
    const int lpix  = tid & 63;
    const int chunk = tid >> 6;
    int start = chunk * qn; if (start > M) start = M;
    int end   = start + qn; if (end > M) end = M;

    const float fxp = x0f + (float)lpix;

    float Tr = 1.0f, ar = 0.0f, ag = 0.0f, abv = 0.0f;
    for (int i = start; i < end; ++i) {
        int gi = s_order[i];
        float4 r0 = s_rec0[gi];
        float4 r1 = s_rec1[gi];
        float  bc = s_bcol[gi];
        float dx = fxp - r0.w;
        float dy = yf  - r1.x;
        float qv = (r0.x*dx)*dx + (r0.y*dx)*dy + (r0.z*dy)*dy; // = -0.5*q
        float G = __expf(fminf(qv, 0.0f));
        float alpha = fminf(r1.y * G, ALPHA_MAX);
        float wgt = alpha * Tr;
        ar  += wgt * r1.z;
        ag  += wgt * r1.w;
        abv += wgt * bc;
        Tr  *= (1.0f - alpha);
    }
    s_part[chunk][lpix] = make_float4(ar, ag, abv, Tr);
    __syncthreads();

    if (chunk == 0) {
        float4 c0 = s_part[0][lpix], c1 = s_part[1][lpix];
        float4 c2 = s_part[2][lpix], c3 = s_part[3][lpix];
        float T0 = c0.w, T01 = T0*c1.w, T012 = T01*c2.w, Tall = T012*c3.w;
        float r  = c0.x + T0*c1.x + T01*c2.x + T012*c3.x;
        float gc = c0.y + T0*c1.y + T01*c2.y + T012*c3.y;
        float bb = c0.z + T0*c1.z + T01*c2.z + T012*c3.z;
        s_out[3*lpix+0] = r  + Tall * bg[0];
        s_out[3*lpix+1] = gc + Tall * bg[1];
        s_out[3*lpix+2] = bb + Tall * bg[2];
    }
    __syncthreads();
    if (tid < PIX*3) {
        const int y  = b >> 2;
        const int x0 = (b & 3) * PIX;
        out[(y * IMG_W + x0) * 3 + tid] = s_out[tid];
    }
}

extern "C" void kernel_launch(void* const* d_in, const int* in_sizes, int n_in,
                              void* d_out, int out_size, void* d_ws, size_t ws_size,
                              hipStream_t stream) {
    const float* pos = (const float*)d_in[0];
    const float* scl = (const float*)d_in[1];
    const float* rot = (const float*)d_in[2];
    const float* opa = (const float*)d_in[3];
    const float* col = (const float*)d_in[4];
    const float* vm  = (const float*)d_in[5];
    const float* bgp = (const float*)d_in[6];
    const int*   fov = (const int*)d_in[7];

    float* out = (float*)d_out;

    gs_fused<<<(IMG_H * IMG_W) / PIX, TPB, 0, stream>>>(
        pos, scl, rot, opa, col, vm, fov, bgp, out);
}